// Round 1
// baseline (787.902 us; speedup 1.0000x reference)
//
#include <hip/hip_runtime.h>
#include <math.h>

#define DIN 128
#define HID 64

// ---------------- wave-level reductions (wave64) ----------------
__device__ inline float wred_sum(float v) {
#pragma unroll
  for (int d = 1; d < 64; d <<= 1) v += __shfl_xor(v, d, 64);
  return v;
}
__device__ inline float wred_max(float v) {
#pragma unroll
  for (int d = 1; d < 64; d <<= 1) v = fmaxf(v, __shfl_xor(v, d, 64));
  return v;
}

// ---------------- CSR build ----------------
__global__ void k_hist(const int* __restrict__ dst, int* __restrict__ cnt, int E) {
  int e = blockIdx.x * 256 + threadIdx.x;
  if (e < E) atomicAdd(&cnt[dst[e]], 1);
}

__global__ __launch_bounds__(1024) void k_scan(const int* __restrict__ cnt,
                                               int* __restrict__ row,
                                               int* __restrict__ cur, int n) {
  __shared__ int part[1024];
  int t = threadIdx.x;
  int chunk = (n + 1023) >> 10;
  int beg = t * chunk;
  int end = min(beg + chunk, n);
  int s = 0;
  for (int i = beg; i < end; ++i) s += cnt[i];
  part[t] = s;
  __syncthreads();
  for (int d = 1; d < 1024; d <<= 1) {
    int v = (t >= d) ? part[t - d] : 0;
    __syncthreads();
    part[t] += v;
    __syncthreads();
  }
  int off = part[t] - s;  // exclusive
  for (int i = beg; i < end; ++i) {
    int c = cnt[i];
    row[i] = off;
    cur[i] = off;
    off += c;
  }
  if (t == 1023) row[n] = part[1023];
}

__global__ void k_scatter(const int* __restrict__ src, const int* __restrict__ dst,
                          int* __restrict__ cur, int* __restrict__ srcs, int E) {
  int e = blockIdx.x * 256 + threadIdx.x;
  if (e < E) {
    int d = dst[e];
    int pos = atomicAdd(&cur[d], 1);
    srcs[pos] = src[e];
  }
}

// ---------------- embedding: h = x @ emb_w + emb_b ----------------
__global__ __launch_bounds__(256) void k_emb(const float* __restrict__ x,
                                             const float* __restrict__ w,
                                             const float* __restrict__ b,
                                             float* __restrict__ h, int n) {
  __shared__ float xs[4][DIN];
  int tid = threadIdx.x;
  int nb = blockIdx.x * 4;
  for (int t = tid; t < 4 * DIN; t += 256) {
    int ni = t >> 7, k = t & 127;
    int gn = nb + ni;
    xs[ni][k] = (gn < n) ? x[(size_t)gn * DIN + k] : 0.f;
  }
  __syncthreads();
  int c = tid & 63, g = tid >> 6;
  int node = nb + g;
  float acc = b[c];
#pragma unroll 8
  for (int k = 0; k < DIN; ++k) acc += xs[g][k] * w[k * HID + c];
  if (node < n) h[(size_t)node * HID + c] = acc;
}

// ---------------- QKV: Q[N,128], KV[N,256] (K then V) ----------------
__global__ __launch_bounds__(256) void k_qkv(const float* __restrict__ h,
                                             const float* __restrict__ Wq,
                                             const float* __restrict__ Wk,
                                             const float* __restrict__ Wv,
                                             float* __restrict__ Q,
                                             float* __restrict__ KV, int n) {
  __shared__ float hs[8][64];
  int tid = threadIdx.x;
  int nb = blockIdx.x * 8;
  for (int t = tid; t < 512; t += 256) {
    int ni = t >> 6, c = t & 63;
    int gn = nb + ni;
    hs[ni][c] = (gn < n) ? h[(size_t)gn * 64 + c] : 0.f;
  }
  __syncthreads();
  int j = tid & 127, g = tid >> 7;
  float aq[4] = {0, 0, 0, 0}, ak[4] = {0, 0, 0, 0}, av[4] = {0, 0, 0, 0};
  for (int c = 0; c < 64; ++c) {
    float wq = Wq[c * 128 + j], wk = Wk[c * 128 + j], wv = Wv[c * 128 + j];
#pragma unroll
    for (int u = 0; u < 4; ++u) {
      float hv = hs[g * 4 + u][c];
      aq[u] += hv * wq;
      ak[u] += hv * wk;
      av[u] += hv * wv;
    }
  }
#pragma unroll
  for (int u = 0; u < 4; ++u) {
    int gn = nb + g * 4 + u;
    if (gn < n) {
      Q[(size_t)gn * 128 + j] = aq[u];
      KV[(size_t)gn * 256 + j] = ak[u];
      KV[(size_t)gn * 256 + 128 + j] = av[u];
    }
  }
}

// ---------------- fused layer: attention aggr -> Wout -> +res -> LN -> FFN ----------------
__global__ __launch_bounds__(256) void k_layer(
    const float* __restrict__ Q, const float* __restrict__ KV,
    const int* __restrict__ row, const int* __restrict__ srcs,
    float* __restrict__ h,
    const float* __restrict__ Wout, const float* __restrict__ bout,
    const float* __restrict__ lng, const float* __restrict__ lnb,
    const float* __restrict__ W1, const float* __restrict__ b1,
    const float* __restrict__ W2, const float* __restrict__ b2, int n) {
  __shared__ float s_aggr[4][128];
  __shared__ float s_h[4][64];
  __shared__ float s_t[4][64];
  int lane = threadIdx.x & 63;
  int w = threadIdx.x >> 6;
  int node = blockIdx.x * 4 + w;
  bool valid = node < n;
  int nn = valid ? node : 0;

  float q0 = Q[(size_t)nn * 128 + lane];
  float q1 = Q[(size_t)nn * 128 + 64 + lane];
  int rs = row[nn], re = row[nn + 1];
  float acc0 = 0.f, acc1 = 0.f, den0 = 0.f, den1 = 0.f;
  for (int e = rs; e < re; ++e) {
    int s = srcs[e];
    const float* kv = KV + (size_t)s * 256;
    float k0 = kv[lane], k1 = kv[64 + lane];
    float v0 = kv[128 + lane], v1 = kv[192 + lane];
    float a0 = wred_sum(q0 * k0) * 0.125f;  // / sqrt(64)
    float a1 = wred_sum(q1 * k1) * 0.125f;
    float w0 = __expf(a0), w1 = __expf(a1);
    den0 += w0;
    den1 += w1;
    acc0 += w0 * v0;
    acc1 += w1 * v1;
  }
  s_aggr[w][lane] = acc0 / (den0 + 1e-16f);
  s_aggr[w][64 + lane] = acc1 / (den1 + 1e-16f);
  __syncthreads();

  // out = aggr @ Wout + bout
  float o = bout[lane];
#pragma unroll 8
  for (int j = 0; j < 128; ++j) o += s_aggr[w][j] * Wout[j * 64 + lane];

  // residual + layernorm
  float xv = o + h[(size_t)nn * 64 + lane];
  float mu = wred_sum(xv) * (1.f / 64.f);
  float xc = xv - mu;
  float var = wred_sum(xc * xc) * (1.f / 64.f);
  float hl = xc * rsqrtf(var + 1e-5f) * lng[lane] + lnb[lane];
  s_h[w][lane] = hl;
  __syncthreads();

  // FFN: h + relu(h@W1+b1)@W2 + b2
  float t = b1[lane];
#pragma unroll 8
  for (int j = 0; j < 64; ++j) t += s_h[w][j] * W1[j * 64 + lane];
  s_t[w][lane] = fmaxf(t, 0.f);
  __syncthreads();
  float o2 = b2[lane];
#pragma unroll 8
  for (int j = 0; j < 64; ++j) o2 += s_t[w][j] * W2[j * 64 + lane];
  if (valid) h[(size_t)nn * 64 + lane] = hl + o2;
}

// ---------------- output: log_softmax(h @ out_w + out_b) ----------------
__global__ __launch_bounds__(256) void k_out(const float* __restrict__ h,
                                             const float* __restrict__ w,
                                             const float* __restrict__ b,
                                             float* __restrict__ out, int n) {
  __shared__ float s_h[4][64];
  int lane = threadIdx.x & 63;
  int wv = threadIdx.x >> 6;
  int node = blockIdx.x * 4 + wv;
  int nn = (node < n) ? node : 0;
  s_h[wv][lane] = h[(size_t)nn * 64 + lane];
  __syncthreads();
  float lv = -3.0e38f;
  if (lane < 40) {
    lv = b[lane];
#pragma unroll 8
    for (int j = 0; j < 64; ++j) lv += s_h[wv][j] * w[j * 40 + lane];
  }
  float m = wred_max(lv);
  float ex = (lane < 40) ? __expf(lv - m) : 0.f;
  float s = wred_sum(ex);
  if (node < n && lane < 40) out[(size_t)node * 40 + lane] = lv - m - logf(s);
}

extern "C" void kernel_launch(void* const* d_in, const int* in_sizes, int n_in,
                              void* d_out, int out_size, void* d_ws, size_t ws_size,
                              hipStream_t stream) {
  const float* x     = (const float*)d_in[0];
  const int*   ei    = (const int*)d_in[1];
  const float* emb_w = (const float*)d_in[2];
  const float* emb_b = (const float*)d_in[3];
  const float* Wq    = (const float*)d_in[4];   // [2,64,128]
  const float* Wk    = (const float*)d_in[5];
  const float* Wv    = (const float*)d_in[6];
  const float* Wout  = (const float*)d_in[7];   // [2,128,64]
  const float* bout  = (const float*)d_in[8];   // [2,64]
  const float* ln_g  = (const float*)d_in[9];
  const float* ln_b  = (const float*)d_in[10];
  const float* W1    = (const float*)d_in[11];  // [2,64,64]
  const float* b1    = (const float*)d_in[12];
  const float* W2    = (const float*)d_in[13];
  const float* b2    = (const float*)d_in[14];
  const float* out_w = (const float*)d_in[15];  // [64,40]
  const float* out_b = (const float*)d_in[16];
  float* out = (float*)d_out;

  const int n = in_sizes[0] / DIN;  // 50000
  const int E = in_sizes[1] / 2;    // 800000

  char* ws = (char*)d_ws;
  size_t off = 0;
  auto alloc = [&](size_t bytes) {
    void* p = ws + off;
    off = (off + bytes + 255) & ~(size_t)255;
    return p;
  };
  float* h   = (float*)alloc((size_t)n * 64 * 4);
  float* Q   = (float*)alloc((size_t)n * 128 * 4);
  float* KV  = (float*)alloc((size_t)n * 256 * 4);
  int* cnt   = (int*)alloc((size_t)n * 4);
  int* rowp  = (int*)alloc((size_t)(n + 1) * 4);
  int* cur   = (int*)alloc((size_t)n * 4);
  int* srcs  = (int*)alloc((size_t)E * 4);

  const int* src = ei;
  const int* dst = ei + E;

  // CSR build (once; reused by both layers)
  hipMemsetAsync(cnt, 0, (size_t)n * 4, stream);
  k_hist<<<(E + 255) / 256, 256, 0, stream>>>(dst, cnt, E);
  k_scan<<<1, 1024, 0, stream>>>(cnt, rowp, cur, n);
  k_scatter<<<(E + 255) / 256, 256, 0, stream>>>(src, dst, cur, srcs, E);

  // embedding
  k_emb<<<(n + 3) / 4, 256, 0, stream>>>(x, emb_w, emb_b, h, n);

  for (int l = 0; l < 2; ++l) {
    k_qkv<<<(n + 7) / 8, 256, 0, stream>>>(h, Wq + (size_t)l * 64 * 128,
                                           Wk + (size_t)l * 64 * 128,
                                           Wv + (size_t)l * 64 * 128, Q, KV, n);
    k_layer<<<(n + 3) / 4, 256, 0, stream>>>(
        Q, KV, rowp, srcs, h, Wout + (size_t)l * 128 * 64, bout + (size_t)l * 64,
        ln_g + (size_t)l * 64, ln_b + (size_t)l * 64, W1 + (size_t)l * 64 * 64,
        b1 + (size_t)l * 64, W2 + (size_t)l * 64 * 64, b2 + (size_t)l * 64, n);
  }

  k_out<<<(n + 3) / 4, 256, 0, stream>>>(h, out_w, out_b, out, n);
}

// Round 2
// 734.657 us; speedup vs baseline: 1.0725x; 1.0725x over previous
//
#include <hip/hip_runtime.h>
#include <math.h>

#define DIN 128
#define HID 64

// ---------------- wave-level reductions (wave64) ----------------
__device__ inline float wred_sum(float v) {
#pragma unroll
  for (int d = 1; d < 64; d <<= 1) v += __shfl_xor(v, d, 64);
  return v;
}
__device__ inline float wred_max(float v) {
#pragma unroll
  for (int d = 1; d < 64; d <<= 1) v = fmaxf(v, __shfl_xor(v, d, 64));
  return v;
}

__device__ inline float h2f(unsigned short u) {
  return (float)__builtin_bit_cast(_Float16, u);
}
__device__ inline unsigned short f2h(float f) {
  return __builtin_bit_cast(unsigned short, (_Float16)f);
}

// ---------------- CSR build ----------------
__global__ void k_hist(const int* __restrict__ dst, int* __restrict__ cnt, int E) {
  int e = blockIdx.x * 256 + threadIdx.x;
  if (e < E) atomicAdd(&cnt[dst[e]], 1);
}

__global__ __launch_bounds__(1024) void k_scan(const int* __restrict__ cnt,
                                               int* __restrict__ row,
                                               int* __restrict__ cur, int n) {
  __shared__ int part[1024];
  int t = threadIdx.x;
  int chunk = (n + 1023) >> 10;
  int beg = t * chunk;
  int end = min(beg + chunk, n);
  int s = 0;
  for (int i = beg; i < end; ++i) s += cnt[i];
  part[t] = s;
  __syncthreads();
  for (int d = 1; d < 1024; d <<= 1) {
    int v = (t >= d) ? part[t - d] : 0;
    __syncthreads();
    part[t] += v;
    __syncthreads();
  }
  int off = part[t] - s;  // exclusive
  for (int i = beg; i < end; ++i) {
    int c = cnt[i];
    row[i] = off;
    cur[i] = off;
    off += c;
  }
  if (t == 1023) row[n] = part[1023];
}

__global__ void k_scatter(const int* __restrict__ src, const int* __restrict__ dst,
                          int* __restrict__ cur, int* __restrict__ srcs, int E) {
  int e = blockIdx.x * 256 + threadIdx.x;
  if (e < E) {
    int d = dst[e];
    int pos = atomicAdd(&cur[d], 1);
    srcs[pos] = src[e];
  }
}

// ---------------- embedding: h = x @ emb_w + emb_b ----------------
__global__ __launch_bounds__(256) void k_emb(const float* __restrict__ x,
                                             const float* __restrict__ w,
                                             const float* __restrict__ b,
                                             float* __restrict__ h, int n) {
  __shared__ float xs[4][DIN];
  int tid = threadIdx.x;
  int nb = blockIdx.x * 4;
  for (int t = tid; t < 4 * DIN; t += 256) {
    int ni = t >> 7, k = t & 127;
    int gn = nb + ni;
    xs[ni][k] = (gn < n) ? x[(size_t)gn * DIN + k] : 0.f;
  }
  __syncthreads();
  int c = tid & 63, g = tid >> 6;
  int node = nb + g;
  float acc = b[c];
#pragma unroll 8
  for (int k = 0; k < DIN; ++k) acc += xs[g][k] * w[k * HID + c];
  if (node < n) h[(size_t)node * HID + c] = acc;
}

// ---------------- QKV: Q[N,128] fp32, KVh[N,256] fp16 ({k0,k1,v0,v1} per col) ----
__global__ __launch_bounds__(256) void k_qkv(const float* __restrict__ h,
                                             const float* __restrict__ Wq,
                                             const float* __restrict__ Wk,
                                             const float* __restrict__ Wv,
                                             float* __restrict__ Q,
                                             unsigned short* __restrict__ KVh, int n) {
  __shared__ float hs[8][64];
  int tid = threadIdx.x;
  int nb = blockIdx.x * 8;
  for (int t = tid; t < 512; t += 256) {
    int ni = t >> 6, c = t & 63;
    int gn = nb + ni;
    hs[ni][c] = (gn < n) ? h[(size_t)gn * 64 + c] : 0.f;
  }
  __syncthreads();
  int j = tid & 127, g = tid >> 7;
  float aq[4] = {0, 0, 0, 0}, ak[4] = {0, 0, 0, 0}, av[4] = {0, 0, 0, 0};
  for (int c = 0; c < 64; ++c) {
    float wq = Wq[c * 128 + j], wk = Wk[c * 128 + j], wv = Wv[c * 128 + j];
#pragma unroll
    for (int u = 0; u < 4; ++u) {
      float hv = hs[g * 4 + u][c];
      aq[u] += hv * wq;
      ak[u] += hv * wk;
      av[u] += hv * wv;
    }
  }
  int head = j >> 6, col = j & 63;
#pragma unroll
  for (int u = 0; u < 4; ++u) {
    int gn = nb + g * 4 + u;
    if (gn < n) {
      Q[(size_t)gn * 128 + j] = aq[u];
      unsigned short* kvp = KVh + (size_t)gn * 256 + 4 * col;
      kvp[head] = f2h(ak[u]);
      kvp[2 + head] = f2h(av[u]);
    }
  }
}

// ---------------- fused layer: attention aggr -> Wout -> +res -> LN -> FFN ----------------
__global__ __launch_bounds__(256) void k_layer(
    const float* __restrict__ Q, const unsigned short* __restrict__ KVh,
    const int* __restrict__ row, const int* __restrict__ srcs,
    float* __restrict__ h,
    const float* __restrict__ Wout, const float* __restrict__ bout,
    const float* __restrict__ lng, const float* __restrict__ lnb,
    const float* __restrict__ W1, const float* __restrict__ b1,
    const float* __restrict__ W2, const float* __restrict__ b2, int n) {
  __shared__ float s_aggr[4][128];
  __shared__ float s_h[4][64];
  __shared__ float s_t[4][64];
  int lane = threadIdx.x & 63;
  int w = threadIdx.x >> 6;
  int node = blockIdx.x * 4 + w;
  bool valid = node < n;
  int nn = valid ? node : 0;

  const ushort4* KV4 = (const ushort4*)KVh;  // [n][64] of {k0,k1,v0,v1}

  float q0 = Q[(size_t)nn * 128 + lane] * 0.125f;       // fold /sqrt(64)
  float q1 = Q[(size_t)nn * 128 + 64 + lane] * 0.125f;
  int rs = row[nn], re = row[nn + 1];
  float acc0 = 0.f, acc1 = 0.f, den0 = 0.f, den1 = 0.f;

  // depth-2 software pipeline on the random KV gather
  ushort4 kvA, kvB;
  if (rs < re) kvA = KV4[(size_t)srcs[rs] * 64 + lane];
  if (rs + 1 < re) kvB = KV4[(size_t)srcs[rs + 1] * 64 + lane];
  for (int e = rs; e < re; ++e) {
    ushort4 cur = kvA;
    kvA = kvB;
    if (e + 2 < re) kvB = KV4[(size_t)srcs[e + 2] * 64 + lane];
    float k0 = h2f(cur.x), k1 = h2f(cur.y);
    float v0 = h2f(cur.z), v1 = h2f(cur.w);
    float a0 = wred_sum(q0 * k0);
    float a1 = wred_sum(q1 * k1);
    float w0 = __expf(a0), w1 = __expf(a1);
    den0 += w0;
    den1 += w1;
    acc0 += w0 * v0;
    acc1 += w1 * v1;
  }
  s_aggr[w][lane] = acc0 / (den0 + 1e-16f);
  s_aggr[w][64 + lane] = acc1 / (den1 + 1e-16f);
  __syncthreads();

  // out = aggr @ Wout + bout
  float o = bout[lane];
#pragma unroll 8
  for (int j = 0; j < 128; ++j) o += s_aggr[w][j] * Wout[j * 64 + lane];

  // residual + layernorm
  float xv = o + h[(size_t)nn * 64 + lane];
  float mu = wred_sum(xv) * (1.f / 64.f);
  float xc = xv - mu;
  float var = wred_sum(xc * xc) * (1.f / 64.f);
  float hl = xc * rsqrtf(var + 1e-5f) * lng[lane] + lnb[lane];
  s_h[w][lane] = hl;
  __syncthreads();

  // FFN: h + relu(h@W1+b1)@W2 + b2
  float t = b1[lane];
#pragma unroll 8
  for (int j = 0; j < 64; ++j) t += s_h[w][j] * W1[j * 64 + lane];
  s_t[w][lane] = fmaxf(t, 0.f);
  __syncthreads();
  float o2 = b2[lane];
#pragma unroll 8
  for (int j = 0; j < 64; ++j) o2 += s_t[w][j] * W2[j * 64 + lane];
  if (valid) h[(size_t)nn * 64 + lane] = hl + o2;
}

// ---------------- output: log_softmax(h @ out_w + out_b) ----------------
__global__ __launch_bounds__(256) void k_out(const float* __restrict__ h,
                                             const float* __restrict__ w,
                                             const float* __restrict__ b,
                                             float* __restrict__ out, int n) {
  __shared__ float s_h[4][64];
  int lane = threadIdx.x & 63;
  int wv = threadIdx.x >> 6;
  int node = blockIdx.x * 4 + wv;
  int nn = (node < n) ? node : 0;
  s_h[wv][lane] = h[(size_t)nn * 64 + lane];
  __syncthreads();
  float lv = -3.0e38f;
  if (lane < 40) {
    lv = b[lane];
#pragma unroll 8
    for (int j = 0; j < 64; ++j) lv += s_h[wv][j] * w[j * 40 + lane];
  }
  float m = wred_max(lv);
  float ex = (lane < 40) ? __expf(lv - m) : 0.f;
  float s = wred_sum(ex);
  if (node < n && lane < 40) out[(size_t)node * 40 + lane] = lv - m - logf(s);
}

extern "C" void kernel_launch(void* const* d_in, const int* in_sizes, int n_in,
                              void* d_out, int out_size, void* d_ws, size_t ws_size,
                              hipStream_t stream) {
  const float* x     = (const float*)d_in[0];
  const int*   ei    = (const int*)d_in[1];
  const float* emb_w = (const float*)d_in[2];
  const float* emb_b = (const float*)d_in[3];
  const float* Wq    = (const float*)d_in[4];   // [2,64,128]
  const float* Wk    = (const float*)d_in[5];
  const float* Wv    = (const float*)d_in[6];
  const float* Wout  = (const float*)d_in[7];   // [2,128,64]
  const float* bout  = (const float*)d_in[8];   // [2,64]
  const float* ln_g  = (const float*)d_in[9];
  const float* ln_b  = (const float*)d_in[10];
  const float* W1    = (const float*)d_in[11];  // [2,64,64]
  const float* b1    = (const float*)d_in[12];
  const float* W2    = (const float*)d_in[13];
  const float* b2    = (const float*)d_in[14];
  const float* out_w = (const float*)d_in[15];  // [64,40]
  const float* out_b = (const float*)d_in[16];
  float* out = (float*)d_out;

  const int n = in_sizes[0] / DIN;  // 50000
  const int E = in_sizes[1] / 2;    // 800000

  char* ws = (char*)d_ws;
  size_t off = 0;
  auto alloc = [&](size_t bytes) {
    void* p = ws + off;
    off = (off + bytes + 255) & ~(size_t)255;
    return p;
  };
  float* h            = (float*)alloc((size_t)n * 64 * 4);
  float* Q            = (float*)alloc((size_t)n * 128 * 4);
  unsigned short* KVh = (unsigned short*)alloc((size_t)n * 256 * 2);
  int* cnt            = (int*)alloc((size_t)n * 4);
  int* rowp           = (int*)alloc((size_t)(n + 1) * 4);
  int* cur            = (int*)alloc((size_t)n * 4);
  int* srcs           = (int*)alloc((size_t)E * 4);

  const int* src = ei;
  const int* dst = ei + E;

  // CSR build (once; reused by both layers)
  hipMemsetAsync(cnt, 0, (size_t)n * 4, stream);
  k_hist<<<(E + 255) / 256, 256, 0, stream>>>(dst, cnt, E);
  k_scan<<<1, 1024, 0, stream>>>(cnt, rowp, cur, n);
  k_scatter<<<(E + 255) / 256, 256, 0, stream>>>(src, dst, cur, srcs, E);

  // embedding
  k_emb<<<(n + 3) / 4, 256, 0, stream>>>(x, emb_w, emb_b, h, n);

  for (int l = 0; l < 2; ++l) {
    k_qkv<<<(n + 7) / 8, 256, 0, stream>>>(h, Wq + (size_t)l * 64 * 128,
                                           Wk + (size_t)l * 64 * 128,
                                           Wv + (size_t)l * 64 * 128, Q, KVh, n);
    k_layer<<<(n + 3) / 4, 256, 0, stream>>>(
        Q, KVh, rowp, srcs, h, Wout + (size_t)l * 128 * 64, bout + (size_t)l * 64,
        ln_g + (size_t)l * 64, ln_b + (size_t)l * 64, W1 + (size_t)l * 64 * 64,
        b1 + (size_t)l * 64, W2 + (size_t)l * 64 * 64, b2 + (size_t)l * 64, n);
  }

  k_out<<<(n + 3) / 4, 256, 0, stream>>>(h, out_w, out_b, out, n);
}

// Round 3
// 630.051 us; speedup vs baseline: 1.2505x; 1.1660x over previous
//
#include <hip/hip_runtime.h>
#include <math.h>

#define DIN 128
#define HID 64

typedef _Float16 h2 __attribute__((ext_vector_type(2)));

// ---------------- wave-level reductions (wave64) ----------------
__device__ inline float wred_sum(float v) {
#pragma unroll
  for (int d = 1; d < 64; d <<= 1) v += __shfl_xor(v, d, 64);
  return v;
}
__device__ inline float wred_max(float v) {
#pragma unroll
  for (int d = 1; d < 64; d <<= 1) v = fmaxf(v, __shfl_xor(v, d, 64));
  return v;
}

__device__ inline unsigned short f2h(float f) {
  return __builtin_bit_cast(unsigned short, (_Float16)f);
}
__device__ inline h2 h2shfl_xor(h2 x, int d) {
  int xi = __builtin_bit_cast(int, x);
  xi = __shfl_xor(xi, d, 64);
  return __builtin_bit_cast(h2, xi);
}

// ---------------- CSR build ----------------
__global__ void k_hist(const int* __restrict__ dst, int* __restrict__ cnt, int E) {
  int e = blockIdx.x * 256 + threadIdx.x;
  if (e < E) atomicAdd(&cnt[dst[e]], 1);
}

__global__ __launch_bounds__(1024) void k_scan(const int* __restrict__ cnt,
                                               int* __restrict__ row,
                                               int* __restrict__ cur, int n) {
  __shared__ int part[1024];
  int t = threadIdx.x;
  int chunk = (n + 1023) >> 10;
  int beg = t * chunk;
  int end = min(beg + chunk, n);
  int s = 0;
  for (int i = beg; i < end; ++i) s += cnt[i];
  part[t] = s;
  __syncthreads();
  for (int d = 1; d < 1024; d <<= 1) {
    int v = (t >= d) ? part[t - d] : 0;
    __syncthreads();
    part[t] += v;
    __syncthreads();
  }
  int off = part[t] - s;  // exclusive
  for (int i = beg; i < end; ++i) {
    int c = cnt[i];
    row[i] = off;
    cur[i] = off;
    off += c;
  }
  if (t == 1023) row[n] = part[1023];
}

__global__ void k_scatter(const int* __restrict__ src, const int* __restrict__ dst,
                          int* __restrict__ cur, int* __restrict__ srcs, int E) {
  int e = blockIdx.x * 256 + threadIdx.x;
  if (e < E) {
    int d = dst[e];
    int pos = atomicAdd(&cur[d], 1);
    srcs[pos] = src[e];
  }
}

// ---------------- embedding: h = x @ emb_w + emb_b ----------------
__global__ __launch_bounds__(256) void k_emb(const float* __restrict__ x,
                                             const float* __restrict__ w,
                                             const float* __restrict__ b,
                                             float* __restrict__ h, int n) {
  __shared__ float xs[4][DIN];
  int tid = threadIdx.x;
  int nb = blockIdx.x * 4;
  for (int t = tid; t < 4 * DIN; t += 256) {
    int ni = t >> 7, k = t & 127;
    int gn = nb + ni;
    xs[ni][k] = (gn < n) ? x[(size_t)gn * DIN + k] : 0.f;
  }
  __syncthreads();
  int c = tid & 63, g = tid >> 6;
  int node = nb + g;
  float acc = b[c];
#pragma unroll 8
  for (int k = 0; k < DIN; ++k) acc += xs[g][k] * w[k * HID + c];
  if (node < n) h[(size_t)node * HID + c] = acc;
}

// ---------------- QKV ----------------
// Layouts (fp16), grouped for 16-lane-per-edge consumption:
//  Qh[node][128]: for g in 0..15: {q0[4g..4g+3], q1[4g..4g+3]}  (q pre-scaled by 1/8)
//  KVh[node][256]: shorts [0,128): g: {k0[4g..4g+3], k1[4g..4g+3]}
//                  shorts [128,256): g: {v0[4g..4g+3], v1[4g..4g+3]}
__global__ __launch_bounds__(256) void k_qkv(const float* __restrict__ h,
                                             const float* __restrict__ Wq,
                                             const float* __restrict__ Wk,
                                             const float* __restrict__ Wv,
                                             unsigned short* __restrict__ Qh,
                                             unsigned short* __restrict__ KVh, int n) {
  __shared__ float hs[8][64];
  int tid = threadIdx.x;
  int nb = blockIdx.x * 8;
  for (int t = tid; t < 512; t += 256) {
    int ni = t >> 6, c = t & 63;
    int gn = nb + ni;
    hs[ni][c] = (gn < n) ? h[(size_t)gn * 64 + c] : 0.f;
  }
  __syncthreads();
  int j = tid & 127, g8 = tid >> 7;
  float aq[4] = {0, 0, 0, 0}, ak[4] = {0, 0, 0, 0}, av[4] = {0, 0, 0, 0};
  for (int c = 0; c < 64; ++c) {
    float wq = Wq[c * 128 + j], wk = Wk[c * 128 + j], wv = Wv[c * 128 + j];
#pragma unroll
    for (int u = 0; u < 4; ++u) {
      float hv = hs[g8 * 4 + u][c];
      aq[u] += hv * wq;
      ak[u] += hv * wk;
      av[u] += hv * wv;
    }
  }
  int head = j >> 6, col = j & 63;
  int g = col >> 2, idx = col & 3;
  int soff = g * 8 + head * 4 + idx;
#pragma unroll
  for (int u = 0; u < 4; ++u) {
    int gn = nb + g8 * 4 + u;
    if (gn < n) {
      Qh[(size_t)gn * 128 + soff] = f2h(aq[u] * 0.125f);
      KVh[(size_t)gn * 256 + soff] = f2h(ak[u]);
      KVh[(size_t)gn * 256 + 128 + soff] = f2h(av[u]);
    }
  }
}

// ---------------- fused layer: attention aggr -> Wout -> +res -> LN -> FFN ----------------
// One node per wave; 4 edges per iteration (16 lanes each).
__global__ __launch_bounds__(256) void k_layer(
    const unsigned short* __restrict__ Qh, const unsigned short* __restrict__ KVh,
    const int* __restrict__ row, const int* __restrict__ srcs,
    float* __restrict__ h,
    const float* __restrict__ Wout, const float* __restrict__ bout,
    const float* __restrict__ lng, const float* __restrict__ lnb,
    const float* __restrict__ W1, const float* __restrict__ b1,
    const float* __restrict__ W2, const float* __restrict__ b2, int n) {
  __shared__ float s_aggr[4][128];
  __shared__ float s_h[4][64];
  __shared__ float s_t[4][64];
  int lane = threadIdx.x & 63;
  int w = threadIdx.x >> 6;
  int node = blockIdx.x * 4 + w;
  bool valid = node < n;
  int nn = valid ? node : 0;

  int g = lane & 15;   // column group (cols 4g..4g+3)
  int gi = lane >> 4;  // edge slot within iteration

  // Q fragment for this lane's 4 columns, both heads (pre-scaled by 1/8)
  uint4 qr = *(const uint4*)(Qh + (size_t)nn * 128 + g * 8);
  h2 q0a = __builtin_bit_cast(h2, qr.x), q0b = __builtin_bit_cast(h2, qr.y);
  h2 q1a = __builtin_bit_cast(h2, qr.z), q1b = __builtin_bit_cast(h2, qr.w);

  int rs = row[nn], re = row[nn + 1];
  float den0 = 0.f, den1 = 0.f;
  h2 acc0a = {0, 0}, acc0b = {0, 0}, acc1a = {0, 0}, acc1b = {0, 0};

  uint4 Kc, Vc;
  {
    int ei = rs + gi;
    int s = (ei < re) ? srcs[ei] : 0;
    const unsigned short* kv = KVh + (size_t)s * 256 + g * 8;
    Kc = *(const uint4*)kv;
    Vc = *(const uint4*)(kv + 128);
  }
  for (int e = rs; e < re; e += 4) {
    uint4 Kn, Vn;
    bool has_next = (e + 4) < re;
    if (has_next) {
      int ei = e + 4 + gi;
      int s = (ei < re) ? srcs[ei] : 0;
      const unsigned short* kv = KVh + (size_t)s * 256 + g * 8;
      Kn = *(const uint4*)kv;
      Vn = *(const uint4*)(kv + 128);
    }
    // scores (both heads) over this lane's 4 columns
    float sc0 = __builtin_amdgcn_fdot2(__builtin_bit_cast(h2, Kc.x), q0a,
               __builtin_amdgcn_fdot2(__builtin_bit_cast(h2, Kc.y), q0b, 0.f, false), false);
    float sc1 = __builtin_amdgcn_fdot2(__builtin_bit_cast(h2, Kc.z), q1a,
               __builtin_amdgcn_fdot2(__builtin_bit_cast(h2, Kc.w), q1b, 0.f, false), false);
#pragma unroll
    for (int d = 1; d < 16; d <<= 1) {
      sc0 += __shfl_xor(sc0, d, 64);
      sc1 += __shfl_xor(sc1, d, 64);
    }
    bool ev = (e + gi) < re;  // uniform within 16-lane group
    float w0 = ev ? __expf(sc0) : 0.f;
    float w1 = ev ? __expf(sc1) : 0.f;
    den0 += w0;
    den1 += w1;
    _Float16 wh0 = (_Float16)w0, wh1 = (_Float16)w1;
    h2 W0 = {wh0, wh0}, W1h = {wh1, wh1};
    acc0a += W0 * __builtin_bit_cast(h2, Vc.x);
    acc0b += W0 * __builtin_bit_cast(h2, Vc.y);
    acc1a += W1h * __builtin_bit_cast(h2, Vc.z);
    acc1b += W1h * __builtin_bit_cast(h2, Vc.w);
    if (has_next) {
      Kc = Kn;
      Vc = Vn;
    }
  }
  // combine the 4 edge-groups (lane bits 4,5)
#pragma unroll
  for (int d = 16; d < 64; d <<= 1) {
    den0 += __shfl_xor(den0, d, 64);
    den1 += __shfl_xor(den1, d, 64);
    acc0a += h2shfl_xor(acc0a, d);
    acc0b += h2shfl_xor(acc0b, d);
    acc1a += h2shfl_xor(acc1a, d);
    acc1b += h2shfl_xor(acc1b, d);
  }
  float inv0 = 1.f / (den0 + 1e-16f);
  float inv1 = 1.f / (den1 + 1e-16f);
  if (lane < 16) {
    s_aggr[w][4 * lane + 0] = (float)acc0a[0] * inv0;
    s_aggr[w][4 * lane + 1] = (float)acc0a[1] * inv0;
    s_aggr[w][4 * lane + 2] = (float)acc0b[0] * inv0;
    s_aggr[w][4 * lane + 3] = (float)acc0b[1] * inv0;
    s_aggr[w][64 + 4 * lane + 0] = (float)acc1a[0] * inv1;
    s_aggr[w][64 + 4 * lane + 1] = (float)acc1a[1] * inv1;
    s_aggr[w][64 + 4 * lane + 2] = (float)acc1b[0] * inv1;
    s_aggr[w][64 + 4 * lane + 3] = (float)acc1b[1] * inv1;
  }
  __syncthreads();

  // out = aggr @ Wout + bout
  float o = bout[lane];
#pragma unroll 8
  for (int j = 0; j < 128; ++j) o += s_aggr[w][j] * Wout[j * 64 + lane];

  // residual + layernorm
  float xv = o + h[(size_t)nn * 64 + lane];
  float mu = wred_sum(xv) * (1.f / 64.f);
  float xc = xv - mu;
  float var = wred_sum(xc * xc) * (1.f / 64.f);
  float hl = xc * rsqrtf(var + 1e-5f) * lng[lane] + lnb[lane];
  s_h[w][lane] = hl;
  __syncthreads();

  // FFN: h + relu(h@W1+b1)@W2 + b2
  float t = b1[lane];
#pragma unroll 8
  for (int j = 0; j < 64; ++j) t += s_h[w][j] * W1[j * 64 + lane];
  s_t[w][lane] = fmaxf(t, 0.f);
  __syncthreads();
  float o2 = b2[lane];
#pragma unroll 8
  for (int j = 0; j < 64; ++j) o2 += s_t[w][j] * W2[j * 64 + lane];
  if (valid) h[(size_t)nn * 64 + lane] = hl + o2;
}

// ---------------- output: log_softmax(h @ out_w + out_b) ----------------
__global__ __launch_bounds__(256) void k_out(const float* __restrict__ h,
                                             const float* __restrict__ w,
                                             const float* __restrict__ b,
                                             float* __restrict__ out, int n) {
  __shared__ float s_h[4][64];
  int lane = threadIdx.x & 63;
  int wv = threadIdx.x >> 6;
  int node = blockIdx.x * 4 + wv;
  int nn = (node < n) ? node : 0;
  s_h[wv][lane] = h[(size_t)nn * 64 + lane];
  __syncthreads();
  float lv = -3.0e38f;
  if (lane < 40) {
    lv = b[lane];
#pragma unroll 8
    for (int j = 0; j < 64; ++j) lv += s_h[wv][j] * w[j * 40 + lane];
  }
  float m = wred_max(lv);
  float ex = (lane < 40) ? __expf(lv - m) : 0.f;
  float s = wred_sum(ex);
  if (node < n && lane < 40) out[(size_t)node * 40 + lane] = lv - m - logf(s);
}

extern "C" void kernel_launch(void* const* d_in, const int* in_sizes, int n_in,
                              void* d_out, int out_size, void* d_ws, size_t ws_size,
                              hipStream_t stream) {
  const float* x     = (const float*)d_in[0];
  const int*   ei    = (const int*)d_in[1];
  const float* emb_w = (const float*)d_in[2];
  const float* emb_b = (const float*)d_in[3];
  const float* Wq    = (const float*)d_in[4];   // [2,64,128]
  const float* Wk    = (const float*)d_in[5];
  const float* Wv    = (const float*)d_in[6];
  const float* Wout  = (const float*)d_in[7];   // [2,128,64]
  const float* bout  = (const float*)d_in[8];   // [2,64]
  const float* ln_g  = (const float*)d_in[9];
  const float* ln_b  = (const float*)d_in[10];
  const float* W1    = (const float*)d_in[11];  // [2,64,64]
  const float* b1    = (const float*)d_in[12];
  const float* W2    = (const float*)d_in[13];
  const float* b2    = (const float*)d_in[14];
  const float* out_w = (const float*)d_in[15];  // [64,40]
  const float* out_b = (const float*)d_in[16];
  float* out = (float*)d_out;

  const int n = in_sizes[0] / DIN;  // 50000
  const int E = in_sizes[1] / 2;    // 800000

  char* ws = (char*)d_ws;
  size_t off = 0;
  auto alloc = [&](size_t bytes) {
    void* p = ws + off;
    off = (off + bytes + 255) & ~(size_t)255;
    return p;
  };
  float* h            = (float*)alloc((size_t)n * 64 * 4);
  unsigned short* Qh  = (unsigned short*)alloc((size_t)n * 128 * 2);
  unsigned short* KVh = (unsigned short*)alloc((size_t)n * 256 * 2);
  int* cnt            = (int*)alloc((size_t)n * 4);
  int* rowp           = (int*)alloc((size_t)(n + 1) * 4);
  int* cur            = (int*)alloc((size_t)n * 4);
  int* srcs           = (int*)alloc((size_t)E * 4);

  const int* src = ei;
  const int* dst = ei + E;

  // CSR build (once; reused by both layers)
  hipMemsetAsync(cnt, 0, (size_t)n * 4, stream);
  k_hist<<<(E + 255) / 256, 256, 0, stream>>>(dst, cnt, E);
  k_scan<<<1, 1024, 0, stream>>>(cnt, rowp, cur, n);
  k_scatter<<<(E + 255) / 256, 256, 0, stream>>>(src, dst, cur, srcs, E);

  // embedding
  k_emb<<<(n + 3) / 4, 256, 0, stream>>>(x, emb_w, emb_b, h, n);

  for (int l = 0; l < 2; ++l) {
    k_qkv<<<(n + 7) / 8, 256, 0, stream>>>(h, Wq + (size_t)l * 64 * 128,
                                           Wk + (size_t)l * 64 * 128,
                                           Wv + (size_t)l * 64 * 128, Qh, KVh, n);
    k_layer<<<(n + 3) / 4, 256, 0, stream>>>(
        Qh, KVh, rowp, srcs, h, Wout + (size_t)l * 128 * 64, bout + (size_t)l * 64,
        ln_g + (size_t)l * 64, ln_b + (size_t)l * 64, W1 + (size_t)l * 64 * 64,
        b1 + (size_t)l * 64, W2 + (size_t)l * 64 * 64, b2 + (size_t)l * 64, n);
  }

  k_out<<<(n + 3) / 4, 256, 0, stream>>>(h, out_w, out_b, out, n);
}